// Round 1
// baseline (337.731 us; speedup 1.0000x reference)
//
#include <hip/hip_runtime.h>

// SelfAttentionHead: B=4, T=4096, C=1024, H=64, causal, f32 in/out.
// Pipeline: prep_w (W -> bf16 transposed) -> qkv_proj (MFMA GEMM, Q pre-scaled
// by 0.125) -> flash attention (online softmax, bf16 MFMA, f32 accum).

typedef short  s16x8 __attribute__((ext_vector_type(8)));
typedef short  s16x4 __attribute__((ext_vector_type(4)));
typedef float  f32x4 __attribute__((ext_vector_type(4)));

constexpr int B = 4, T = 4096, C = 1024, H = 64;
constexpr int M = B * T;                    // 16384 tokens
constexpr float LOG2E = 1.44269504088896340736f;

__device__ __forceinline__ unsigned short f2bf(float f) {
    union { float f; unsigned u; } v; v.f = f;
    unsigned r = v.u + 0x7fffu + ((v.u >> 16) & 1u);   // round-to-nearest-even
    return (unsigned short)(r >> 16);
}

// ---------------------------------------------------------------------------
// Kernel 1: Wt[n][k] = W_{n/64}[k][n%64] as bf16.  n in [0,192), k in [0,1024).
// ---------------------------------------------------------------------------
__global__ void prep_w(const float* __restrict__ Wq, const float* __restrict__ Wk,
                       const float* __restrict__ Wv, unsigned short* __restrict__ Wt) {
    const int n = blockIdx.x;                       // 0..191
    const float* W = (n < 64) ? Wq : (n < 128 ? Wk : Wv);
    const int col = n & 63;
    for (int k = threadIdx.x; k < C; k += blockDim.x)
        Wt[(size_t)n * C + k] = f2bf(W[(size_t)k * H + col]);
}

// ---------------------------------------------------------------------------
// Kernel 2: fused QKV projection.  GEMM M=16384,K=1024,N=192 (bf16 MFMA).
// 256 blocks x 256 threads; block = 64 rows; wave = 16 rows x 192 cols.
// Q output pre-scaled by 0.125 (= H^-0.5, exact in bf16).
// ---------------------------------------------------------------------------
__global__ __launch_bounds__(256) void qkv_proj(
    const float* __restrict__ x, const unsigned short* __restrict__ Wt,
    unsigned short* __restrict__ Q, unsigned short* __restrict__ K,
    unsigned short* __restrict__ V) {
    __shared__ __align__(16) unsigned short xs[64 * 64];   // 64 rows x 64 k, bf16, swizzled
    const int t = threadIdx.x;
    const int lane = t & 63, w = t >> 6;
    const int rowbase = blockIdx.x * 64;

    f32x4 acc[12];
#pragma unroll
    for (int i = 0; i < 12; ++i) acc[i] = (f32x4){0.f, 0.f, 0.f, 0.f};

    for (int kc = 0; kc < C; kc += 64) {
        __syncthreads();
        // stage x chunk [64 rows][64 k] f32 -> bf16, XOR-swizzled rows
#pragma unroll
        for (int i = 0; i < 4; ++i) {
            int idx4 = t + i * 256;                 // float4 chunk id, 1024 total
            int row = idx4 >> 4, col = (idx4 & 15) * 4;
            f32x4 v = *(const f32x4*)(x + (size_t)(rowbase + row) * C + kc + col);
            s16x4 h;
            h[0] = (short)f2bf(v[0]); h[1] = (short)f2bf(v[1]);
            h[2] = (short)f2bf(v[2]); h[3] = (short)f2bf(v[3]);
            int off = row * 64 + (col ^ ((row & 7) << 3));
            *(s16x4*)&xs[off] = h;
        }
        __syncthreads();
#pragma unroll
        for (int ks2 = 0; ks2 < 2; ++ks2) {
            const int arow = w * 16 + (lane & 15);
            const int ak = ks2 * 32 + ((lane >> 4) << 3);
            s16x8 a = *(const s16x8*)&xs[arow * 64 + (ak ^ ((arow & 7) << 3))];
#pragma unroll
            for (int nt = 0; nt < 12; ++nt) {
                int n = nt * 16 + (lane & 15);
                s16x8 bf = *(const s16x8*)(Wt + (size_t)n * C + kc + ks2 * 32 + ((lane >> 4) << 3));
                acc[nt] = __builtin_amdgcn_mfma_f32_16x16x32_bf16(a, bf, acc[nt], 0, 0, 0);
            }
        }
    }
    // epilogue: D layout col=lane&15, row=4*(lane>>4)+r  [HW-verified]
#pragma unroll
    for (int nt = 0; nt < 12; ++nt) {
        int n = nt * 16 + (lane & 15);
#pragma unroll
        for (int r = 0; r < 4; ++r) {
            int row = rowbase + w * 16 + ((lane >> 4) << 2) + r;
            float val = acc[nt][r];
            if (n < 64)       Q[(size_t)row * H + n]         = f2bf(val * 0.125f);
            else if (n < 128) K[(size_t)row * H + (n - 64)]  = f2bf(val);
            else              V[(size_t)row * H + (n - 128)] = f2bf(val);
        }
    }
}

// ---------------------------------------------------------------------------
// Kernel 3: causal flash attention.  512 blocks (B x T/32), 128 threads
// (2 waves x 16 q-rows).  KV tiles of 64 keys; K row-major swizzled LDS,
// V transposed swizzled LDS; P via per-wave swizzled LDS round-trip.
// ---------------------------------------------------------------------------
__global__ __launch_bounds__(128) void attn(
    const unsigned short* __restrict__ Qg, const unsigned short* __restrict__ Kg,
    const unsigned short* __restrict__ Vg, float* __restrict__ out) {
    __shared__ __align__(16) unsigned short ks[64 * 64];       // [key][h]  swizzled
    __shared__ __align__(16) unsigned short vt[64 * 64];       // [h][key]  swizzled
    __shared__ __align__(16) unsigned short ps[2 * 16 * 64];   // per-wave P  [q][key] swizzled

    const int t = threadIdx.x, lane = t & 63, w = t >> 6;
    const int qt = (T / 32 - 1) - (int)(blockIdx.x & (T / 32 - 1));  // heavy tiles first
    const int b  = blockIdx.x >> 7;
    const int q0 = qt * 32 + w * 16;             // this wave's first q row
    const int grow = b * T + q0;

    // Q fragments (already scaled by 0.125): A-layout row=lane&15, k=8*(lane>>4)+j
    s16x8 aq[2];
#pragma unroll
    for (int kst = 0; kst < 2; ++kst)
        aq[kst] = *(const s16x8*)(Qg + (size_t)(grow + (lane & 15)) * H + kst * 32 + ((lane >> 4) << 3));

    f32x4 oacc[4];
#pragma unroll
    for (int nt = 0; nt < 4; ++nt) oacc[nt] = (f32x4){0.f, 0.f, 0.f, 0.f};
    float m_run[4], l_run[4];
#pragma unroll
    for (int r = 0; r < 4; ++r) { m_run[r] = -INFINITY; l_run[r] = 0.f; }

    const int q_hi = qt * 32 + 31;
    const int nkv = (q_hi >> 6) + 1;
    unsigned short* myps = ps + w * 16 * 64;

    for (int kv = 0; kv < nkv; ++kv) {
        const int kvbase = kv * 64;
        __syncthreads();
        // ---- stage K tile (row-major, swizzled) and V tile (transposed, swizzled)
#pragma unroll
        for (int i = 0; i < 4; ++i) {
            int c16 = t + i * 128;                  // 512 chunks of 8 bf16
            int row = c16 >> 3, colb = (c16 & 7) * 8;
            size_t gsrc = (size_t)(b * T + kvbase + row) * H + colb;
            s16x8 kr = *(const s16x8*)(Kg + gsrc);
            *(s16x8*)&ks[row * 64 + (colb ^ ((row & 7) << 3))] = kr;
            s16x8 vr = *(const s16x8*)(Vg + gsrc);
#pragma unroll
            for (int j = 0; j < 8; ++j) {
                int hh = colb + j;
                vt[hh * 64 + (row ^ ((hh & 7) << 3))] = (unsigned short)vr[j];
            }
        }
        __syncthreads();

        // ---- S = Q K^T  (16 q x 64 keys per wave)
        f32x4 s[4];
#pragma unroll
        for (int nt = 0; nt < 4; ++nt) s[nt] = (f32x4){0.f, 0.f, 0.f, 0.f};
#pragma unroll
        for (int kst = 0; kst < 2; ++kst) {
#pragma unroll
            for (int nt = 0; nt < 4; ++nt) {
                int key = nt * 16 + (lane & 15);
                s16x8 bf = *(const s16x8*)&ks[key * 64 + ((kst * 32 + ((lane >> 4) << 3)) ^ ((key & 7) << 3))];
                s[nt] = __builtin_amdgcn_mfma_f32_16x16x32_bf16(aq[kst], bf, s[nt], 0, 0, 0);
            }
        }

        // ---- causal mask (cheap, applied every tile)
        const int rq0 = q0 + ((lane >> 4) << 2);
#pragma unroll
        for (int nt = 0; nt < 4; ++nt) {
            int key = kvbase + nt * 16 + (lane & 15);
#pragma unroll
            for (int r = 0; r < 4; ++r)
                if (key > rq0 + r) s[nt][r] = -INFINITY;
        }

        // ---- online softmax (rows spread over 16-lane groups)
#pragma unroll
        for (int r = 0; r < 4; ++r) {
            float mx = fmaxf(fmaxf(s[0][r], s[1][r]), fmaxf(s[2][r], s[3][r]));
            mx = fmaxf(mx, __shfl_xor(mx, 1));
            mx = fmaxf(mx, __shfl_xor(mx, 2));
            mx = fmaxf(mx, __shfl_xor(mx, 4));
            mx = fmaxf(mx, __shfl_xor(mx, 8));
            float mnew = fmaxf(m_run[r], mx);
            float scale = exp2f((m_run[r] - mnew) * LOG2E);
            float rs = 0.f;
#pragma unroll
            for (int nt = 0; nt < 4; ++nt) {
                float p = exp2f((s[nt][r] - mnew) * LOG2E);
                s[nt][r] = p;
                rs += p;
            }
            rs += __shfl_xor(rs, 1);
            rs += __shfl_xor(rs, 2);
            rs += __shfl_xor(rs, 4);
            rs += __shfl_xor(rs, 8);
            l_run[r] = l_run[r] * scale + rs;
            m_run[r] = mnew;
#pragma unroll
            for (int nt = 0; nt < 4; ++nt) oacc[nt][r] *= scale;
        }

        // ---- P (D-layout) -> per-wave LDS (swizzled) -> A-layout fragments
#pragma unroll
        for (int nt = 0; nt < 4; ++nt) {
            int colk = nt * 16 + (lane & 15);
#pragma unroll
            for (int r = 0; r < 4; ++r) {
                int row = ((lane >> 4) << 2) + r;
                myps[row * 64 + (colk ^ ((row & 7) << 3))] = f2bf(s[nt][r]);
            }
        }

        // ---- O += P V
#pragma unroll
        for (int kst = 0; kst < 2; ++kst) {
            int arow = lane & 15;
            s16x8 pa = *(const s16x8*)&myps[arow * 64 + ((kst * 32 + ((lane >> 4) << 3)) ^ ((arow & 7) << 3))];
#pragma unroll
            for (int nt = 0; nt < 4; ++nt) {
                int hh = nt * 16 + (lane & 15);
                s16x8 vb = *(const s16x8*)&vt[hh * 64 + ((kst * 32 + ((lane >> 4) << 3)) ^ ((hh & 7) << 3))];
                oacc[nt] = __builtin_amdgcn_mfma_f32_16x16x32_bf16(pa, vb, oacc[nt], 0, 0, 0);
            }
        }
    }

    // ---- epilogue: out[b,q,h] = O / l
#pragma unroll
    for (int r = 0; r < 4; ++r) {
        float inv = 1.0f / l_run[r];
        int q = q0 + ((lane >> 4) << 2) + r;
#pragma unroll
        for (int nt = 0; nt < 4; ++nt)
            out[(size_t)(b * T + q) * H + nt * 16 + (lane & 15)] = oacc[nt][r] * inv;
    }
}

// ---------------------------------------------------------------------------
extern "C" void kernel_launch(void* const* d_in, const int* in_sizes, int n_in,
                              void* d_out, int out_size, void* d_ws, size_t ws_size,
                              hipStream_t stream) {
    (void)in_sizes; (void)n_in; (void)out_size; (void)ws_size;
    const float* x  = (const float*)d_in[0];
    const float* Wq = (const float*)d_in[1];
    const float* Wk = (const float*)d_in[2];
    const float* Wv = (const float*)d_in[3];
    float* out = (float*)d_out;

    char* ws = (char*)d_ws;
    unsigned short* Q  = (unsigned short*)(ws);
    unsigned short* K  = (unsigned short*)(ws + (size_t)1 * M * H * 2);
    unsigned short* V  = (unsigned short*)(ws + (size_t)2 * M * H * 2);
    unsigned short* Wt = (unsigned short*)(ws + (size_t)3 * M * H * 2);
    // total workspace: 3*2MB + 384KB = 6.67MB

    prep_w<<<192, 256, 0, stream>>>(Wq, Wk, Wv, Wt);
    qkv_proj<<<M / 64, 256, 0, stream>>>(x, Wt, Q, K, V);
    attn<<<B * (T / 32), 128, 0, stream>>>(Q, K, V, out);
}

// Round 2
// 171.289 us; speedup vs baseline: 1.9717x; 1.9717x over previous
//
#include <hip/hip_runtime.h>

// SelfAttentionHead: B=4, T=4096, C=1024, H=64, causal, f32 in/out.
// prep_w -> qkv_proj (LDS-free MFMA GEMM) -> vtrans (V -> VT) ->
// attn (paired q-tiles, 4-way KV split per tile, barrier-free inner loop).

typedef short  s16x8 __attribute__((ext_vector_type(8)));
typedef float  f32x4 __attribute__((ext_vector_type(4)));

constexpr int B = 4, T = 4096, C = 1024, H = 64;
constexpr int M = B * T;                    // 16384 tokens
constexpr float LOG2E = 1.44269504088896340736f;

__device__ __forceinline__ unsigned short f2bf(float f) {
    union { float f; unsigned u; } v; v.f = f;
    unsigned r = v.u + 0x7fffu + ((v.u >> 16) & 1u);   // RNE
    return (unsigned short)(r >> 16);
}

// ---------------------------------------------------------------------------
// Kernel 1: Wt[n][k] = W_{n/64}[k][n%64] as bf16.
// ---------------------------------------------------------------------------
__global__ void prep_w(const float* __restrict__ Wq, const float* __restrict__ Wk,
                       const float* __restrict__ Wv, unsigned short* __restrict__ Wt) {
    const int n = blockIdx.x;                       // 0..191
    const float* W = (n < 64) ? Wq : (n < 128 ? Wk : Wv);
    const int col = n & 63;
    for (int k = threadIdx.x; k < C; k += blockDim.x)
        Wt[(size_t)n * C + k] = f2bf(W[(size_t)k * H + col]);
}

// ---------------------------------------------------------------------------
// Kernel 2: fused QKV projection, LDS-free.  M=16384,K=1024,N=192 bf16 MFMA.
// 512 blocks x 128 thr (2 waves x 16 rows).  Q pre-scaled by 0.125.
// ---------------------------------------------------------------------------
__global__ __launch_bounds__(128) void qkv_proj(
    const float* __restrict__ x, const unsigned short* __restrict__ Wt,
    unsigned short* __restrict__ Q, unsigned short* __restrict__ K,
    unsigned short* __restrict__ V) {
    const int t = threadIdx.x, lane = t & 63, w = t >> 6;
    const int i = lane & 15, g = lane >> 4;
    const int rowbase = blockIdx.x * 32 + w * 16;
    const float* xrow = x + (size_t)(rowbase + i) * C + g * 8;
    const unsigned short* brow = Wt + (size_t)i * C + g * 8;

    f32x4 acc[12];
#pragma unroll
    for (int n = 0; n < 12; ++n) acc[n] = (f32x4){0.f, 0.f, 0.f, 0.f};

#pragma unroll 2
    for (int kc = 0; kc < C; kc += 32) {
        f32x4 a0 = *(const f32x4*)(xrow + kc);
        f32x4 a1 = *(const f32x4*)(xrow + kc + 4);
        s16x8 a;
        a[0] = (short)f2bf(a0[0]); a[1] = (short)f2bf(a0[1]);
        a[2] = (short)f2bf(a0[2]); a[3] = (short)f2bf(a0[3]);
        a[4] = (short)f2bf(a1[0]); a[5] = (short)f2bf(a1[1]);
        a[6] = (short)f2bf(a1[2]); a[7] = (short)f2bf(a1[3]);
#pragma unroll
        for (int nt = 0; nt < 12; ++nt) {
            s16x8 bf = *(const s16x8*)(brow + (size_t)nt * 16 * C + kc);
            acc[nt] = __builtin_amdgcn_mfma_f32_16x16x32_bf16(a, bf, acc[nt], 0, 0, 0);
        }
    }
    // D layout: col=lane&15, row=4*(lane>>4)+r
#pragma unroll
    for (int nt = 0; nt < 12; ++nt) {
        int n = nt * 16 + i;
#pragma unroll
        for (int r = 0; r < 4; ++r) {
            int row = rowbase + g * 4 + r;
            float val = acc[nt][r];
            if (n < 64)       Q[(size_t)row * H + n]         = f2bf(val * 0.125f);
            else if (n < 128) K[(size_t)row * H + (n - 64)]  = f2bf(val);
            else              V[(size_t)row * H + (n - 128)] = f2bf(val);
        }
    }
}

// ---------------------------------------------------------------------------
// Kernel 3: VT[b][h][t] = V[b][t][h].  256 blocks x 256 thr, 64x64 tiles.
// ---------------------------------------------------------------------------
__global__ __launch_bounds__(256) void vtrans(const unsigned short* __restrict__ V,
                                              unsigned short* __restrict__ VT) {
    __shared__ __align__(16) unsigned short tile[64][72];
    const int b = blockIdx.x >> 6, t0 = (blockIdx.x & 63) * 64;
    const int tid = threadIdx.x;
    {
        int row = tid >> 2, col = (tid & 3) * 16;
        s16x8 v0 = *(const s16x8*)(V + (size_t)(b * T + t0 + row) * H + col);
        s16x8 v1 = *(const s16x8*)(V + (size_t)(b * T + t0 + row) * H + col + 8);
        *(s16x8*)&tile[row][col]     = v0;
        *(s16x8*)&tile[row][col + 8] = v1;
    }
    __syncthreads();
    {
        int h = tid >> 2, tcol = (tid & 3) * 16;
        s16x8 o0, o1;
#pragma unroll
        for (int j = 0; j < 8; ++j) o0[j] = (short)tile[tcol + j][h];
#pragma unroll
        for (int j = 0; j < 8; ++j) o1[j] = (short)tile[tcol + 8 + j][h];
        unsigned short* dst = VT + (size_t)(b * H + h) * T + t0 + tcol;
        *(s16x8*)dst       = o0;
        *(s16x8*)(dst + 8) = o1;
    }
}

// ---------------------------------------------------------------------------
// Kernel 4: causal flash attention.
// 512 blocks x 512 thr (8 waves).  Block = batch b, pair p: group 0 (waves
// 0-3) handles q-tile p, group 1 (waves 4-7) handles q-tile 255-p; within a
// group, wave sp handles KV tiles {sp, sp+4, ...}.  Barrier-free inner loop:
// K/VT fragments direct from global; P via per-wave swizzled LDS.
// Partial (m,l,O) merged across the 4 splits at the end.
// ---------------------------------------------------------------------------
__global__ __launch_bounds__(512, 4) void attn(
    const unsigned short* __restrict__ Qg, const unsigned short* __restrict__ Kg,
    const unsigned short* __restrict__ VTg, float* __restrict__ out) {
    __shared__ __align__(16) unsigned short ps[8][16 * 64];
    __shared__ __align__(16) float Olds[8][16][68];
    __shared__ float mS[8][16], lS[8][16];

    const int t = threadIdx.x, lane = t & 63, w = t >> 6;
    const int grp = w >> 2, sp = w & 3;
    const int p = blockIdx.x & 127, b = blockIdx.x >> 7;
    const int qt = grp ? (255 - p) : p;
    const int q0 = qt * 16;
    const int i = lane & 15, g = lane >> 4;

    const unsigned short* Qrow = Qg + (size_t)(b * T + q0 + i) * H;
    s16x8 aq0 = *(const s16x8*)(Qrow + g * 8);
    s16x8 aq1 = *(const s16x8*)(Qrow + 32 + g * 8);

    f32x4 oacc[4];
#pragma unroll
    for (int nt = 0; nt < 4; ++nt) oacc[nt] = (f32x4){0.f, 0.f, 0.f, 0.f};
    float m_run[4], l_run[4];
#pragma unroll
    for (int r = 0; r < 4; ++r) { m_run[r] = -INFINITY; l_run[r] = 0.f; }

    const int nkv = ((q0 + 15) >> 6) + 1;
    unsigned short* myps = ps[w];
    const unsigned short* Kb  = Kg  + (size_t)b * T * H;
    const unsigned short* Vb  = VTg + (size_t)b * H * T;

    for (int tile = sp; tile < nkv; tile += 4) {
        const int kv = tile * 64;

        // ---- K fragments (B-layout direct from global)
        s16x8 kb[8];
#pragma unroll
        for (int kst = 0; kst < 2; ++kst)
#pragma unroll
            for (int nt = 0; nt < 4; ++nt)
                kb[kst * 4 + nt] = *(const s16x8*)(Kb + (size_t)(kv + nt * 16 + i) * H + kst * 32 + g * 8);

        // ---- S = Q K^T
        f32x4 s[4];
#pragma unroll
        for (int nt = 0; nt < 4; ++nt) s[nt] = (f32x4){0.f, 0.f, 0.f, 0.f};
#pragma unroll
        for (int nt = 0; nt < 4; ++nt)
            s[nt] = __builtin_amdgcn_mfma_f32_16x16x32_bf16(aq0, kb[nt], s[nt], 0, 0, 0);
#pragma unroll
        for (int nt = 0; nt < 4; ++nt)
            s[nt] = __builtin_amdgcn_mfma_f32_16x16x32_bf16(aq1, kb[4 + nt], s[nt], 0, 0, 0);

        // ---- VT fragments for PV (issue early; independent of softmax)
        s16x8 vb[8];
#pragma unroll
        for (int kst = 0; kst < 2; ++kst)
#pragma unroll
            for (int nt = 0; nt < 4; ++nt)
                vb[kst * 4 + nt] = *(const s16x8*)(Vb + (size_t)(nt * 16 + i) * T + kv + kst * 32 + g * 8);

        // ---- causal mask: lane holds q = q0+4g+r, key = kv + nt*16 + i
        const int rq0 = q0 + g * 4;
#pragma unroll
        for (int nt = 0; nt < 4; ++nt) {
            int key = kv + nt * 16 + i;
#pragma unroll
            for (int r = 0; r < 4; ++r)
                if (key > rq0 + r) s[nt][r] = -INFINITY;
        }

        // ---- online softmax (key dim: 4 nt regs + 16-lane groups)
#pragma unroll
        for (int r = 0; r < 4; ++r) {
            float mx = fmaxf(fmaxf(s[0][r], s[1][r]), fmaxf(s[2][r], s[3][r]));
            mx = fmaxf(mx, __shfl_xor(mx, 1));
            mx = fmaxf(mx, __shfl_xor(mx, 2));
            mx = fmaxf(mx, __shfl_xor(mx, 4));
            mx = fmaxf(mx, __shfl_xor(mx, 8));
            float mnew = fmaxf(m_run[r], mx);
            float scale = exp2f((m_run[r] - mnew) * LOG2E);
            float rs = 0.f;
#pragma unroll
            for (int nt = 0; nt < 4; ++nt) {
                float pv = exp2f((s[nt][r] - mnew) * LOG2E);
                s[nt][r] = pv;
                rs += pv;
            }
            rs += __shfl_xor(rs, 1);
            rs += __shfl_xor(rs, 2);
            rs += __shfl_xor(rs, 4);
            rs += __shfl_xor(rs, 8);
            l_run[r] = l_run[r] * scale + rs;
            m_run[r] = mnew;
#pragma unroll
            for (int nt = 0; nt < 4; ++nt) oacc[nt][r] *= scale;
        }

        // ---- P (D-layout) -> per-wave LDS (swizzled) -> A-layout
#pragma unroll
        for (int nt = 0; nt < 4; ++nt) {
            int colk = nt * 16 + i;
#pragma unroll
            for (int r = 0; r < 4; ++r) {
                int row = g * 4 + r;
                myps[row * 64 + (colk ^ ((row & 7) << 3))] = f2bf(s[nt][r]);
            }
        }

        // ---- O += P V
#pragma unroll
        for (int kst = 0; kst < 2; ++kst) {
            s16x8 pa = *(const s16x8*)&myps[i * 64 + ((kst * 32 + g * 8) ^ ((i & 7) << 3))];
#pragma unroll
            for (int nt = 0; nt < 4; ++nt)
                oacc[nt] = __builtin_amdgcn_mfma_f32_16x16x32_bf16(pa, vb[kst * 4 + nt], oacc[nt], 0, 0, 0);
        }
    }

    // ---- write partial (m, l, O) and merge the 4 KV splits
#pragma unroll
    for (int nt = 0; nt < 4; ++nt)
#pragma unroll
        for (int r = 0; r < 4; ++r)
            Olds[w][g * 4 + r][nt * 16 + i] = oacc[nt][r];
    if (i == 0) {
#pragma unroll
        for (int r = 0; r < 4; ++r) { mS[w][g * 4 + r] = m_run[r]; lS[w][g * 4 + r] = l_run[r]; }
    }
    __syncthreads();

    {
        const int grp2 = t >> 8, idx = t & 255;
        const int q = idx >> 4, hc = (idx & 15) * 4;
        const int w0 = grp2 * 4;
        float Mx = fmaxf(fmaxf(mS[w0][q], mS[w0 + 1][q]), fmaxf(mS[w0 + 2][q], mS[w0 + 3][q]));
        float L = 0.f;
        f32x4 o = (f32x4){0.f, 0.f, 0.f, 0.f};
#pragma unroll
        for (int s4 = 0; s4 < 4; ++s4) {
            float wg = exp2f((mS[w0 + s4][q] - Mx) * LOG2E);
            L += wg * lS[w0 + s4][q];
            f32x4 ov = *(const f32x4*)&Olds[w0 + s4][q][hc];
            o[0] += wg * ov[0]; o[1] += wg * ov[1]; o[2] += wg * ov[2]; o[3] += wg * ov[3];
        }
        const int qq = (grp2 ? (255 - p) : p) * 16 + q;
        float inv = 1.0f / L;
        f32x4 res = (f32x4){o[0] * inv, o[1] * inv, o[2] * inv, o[3] * inv};
        *(f32x4*)(out + (size_t)(b * T + qq) * H + hc) = res;
    }
}

// ---------------------------------------------------------------------------
extern "C" void kernel_launch(void* const* d_in, const int* in_sizes, int n_in,
                              void* d_out, int out_size, void* d_ws, size_t ws_size,
                              hipStream_t stream) {
    (void)in_sizes; (void)n_in; (void)out_size; (void)ws_size;
    const float* x  = (const float*)d_in[0];
    const float* Wq = (const float*)d_in[1];
    const float* Wk = (const float*)d_in[2];
    const float* Wv = (const float*)d_in[3];
    float* out = (float*)d_out;

    char* ws = (char*)d_ws;
    unsigned short* Q  = (unsigned short*)(ws);
    unsigned short* K  = (unsigned short*)(ws + (size_t)1 * M * H * 2);
    unsigned short* V  = (unsigned short*)(ws + (size_t)2 * M * H * 2);
    unsigned short* VT = (unsigned short*)(ws + (size_t)3 * M * H * 2);
    unsigned short* Wt = (unsigned short*)(ws + (size_t)4 * M * H * 2);
    // workspace: 4*2MB + 384KB = 8.4MB

    prep_w<<<192, 256, 0, stream>>>(Wq, Wk, Wv, Wt);
    qkv_proj<<<M / 32, 128, 0, stream>>>(x, Wt, Q, K, V);
    vtrans<<<B * (T / 64), 256, 0, stream>>>(V, VT);
    attn<<<B * 128, 512, 0, stream>>>(Q, K, VT, out);
}

// Round 3
// 148.104 us; speedup vs baseline: 2.2804x; 1.1565x over previous
//
#include <hip/hip_runtime.h>

// SelfAttentionHead: B=4, T=4096, C=1024, H=64, causal, f32 in/out.
// prep_w -> qkv_proj (LDS-free MFMA GEMM, N-split 4 waves/16-row block) ->
// vtrans (V -> VT) -> attn (paired q-tiles, 4-way KV split, barrier-free).

typedef short  s16x8 __attribute__((ext_vector_type(8)));
typedef float  f32x4 __attribute__((ext_vector_type(4)));

constexpr int B = 4, T = 4096, C = 1024, H = 64;
constexpr int M = B * T;                    // 16384 tokens
constexpr float LOG2E = 1.44269504088896340736f;

__device__ __forceinline__ unsigned short f2bf(float f) {
    union { float f; unsigned u; } v; v.f = f;
    unsigned r = v.u + 0x7fffu + ((v.u >> 16) & 1u);   // RNE
    return (unsigned short)(r >> 16);
}

// ---------------------------------------------------------------------------
// Kernel 1: Wt[n][k] = W_{n/64}[k][n%64] as bf16.
// ---------------------------------------------------------------------------
__global__ void prep_w(const float* __restrict__ Wq, const float* __restrict__ Wk,
                       const float* __restrict__ Wv, unsigned short* __restrict__ Wt) {
    const int n = blockIdx.x;                       // 0..191
    const float* W = (n < 64) ? Wq : (n < 128 ? Wk : Wv);
    const int col = n & 63;
    for (int k = threadIdx.x; k < C; k += blockDim.x)
        Wt[(size_t)n * C + k] = f2bf(W[(size_t)k * H + col]);
}

// ---------------------------------------------------------------------------
// Kernel 2: fused QKV projection, LDS-free.  M=16384,K=1024,N=192 bf16 MFMA.
// 1024 blocks x 256 thr (4 waves).  Block = 16 rows x 192 cols; wave w owns
// N-tiles {3w..3w+2} (48 cols).  All 4 waves read the same x rows (L1 reuse).
// Q output pre-scaled by 0.125.
// ---------------------------------------------------------------------------
__global__ __launch_bounds__(256) void qkv_proj(
    const float* __restrict__ x, const unsigned short* __restrict__ Wt,
    unsigned short* __restrict__ Q, unsigned short* __restrict__ K,
    unsigned short* __restrict__ V) {
    const int t = threadIdx.x, lane = t & 63, w = t >> 6;
    const int i = lane & 15, g = lane >> 4;
    const int rowbase = blockIdx.x * 16;
    const float* xrow = x + (size_t)(rowbase + i) * C + g * 8;
    const unsigned short* brow = Wt + (size_t)(w * 48 + i) * C + g * 8;

    f32x4 acc[3];
#pragma unroll
    for (int n = 0; n < 3; ++n) acc[n] = (f32x4){0.f, 0.f, 0.f, 0.f};

#pragma unroll 4
    for (int kc = 0; kc < C; kc += 32) {
        f32x4 a0 = *(const f32x4*)(xrow + kc);
        f32x4 a1 = *(const f32x4*)(xrow + kc + 4);
        s16x8 a;
        a[0] = (short)f2bf(a0[0]); a[1] = (short)f2bf(a0[1]);
        a[2] = (short)f2bf(a0[2]); a[3] = (short)f2bf(a0[3]);
        a[4] = (short)f2bf(a1[0]); a[5] = (short)f2bf(a1[1]);
        a[6] = (short)f2bf(a1[2]); a[7] = (short)f2bf(a1[3]);
#pragma unroll
        for (int nt = 0; nt < 3; ++nt) {
            s16x8 bf = *(const s16x8*)(brow + (size_t)nt * 16 * C + kc);
            acc[nt] = __builtin_amdgcn_mfma_f32_16x16x32_bf16(a, bf, acc[nt], 0, 0, 0);
        }
    }
    // D layout: col=lane&15, row=4*(lane>>4)+r
#pragma unroll
    for (int nt = 0; nt < 3; ++nt) {
        int n = w * 48 + nt * 16 + i;
#pragma unroll
        for (int r = 0; r < 4; ++r) {
            int row = rowbase + g * 4 + r;
            float val = acc[nt][r];
            if (n < 64)       Q[(size_t)row * H + n]         = f2bf(val * 0.125f);
            else if (n < 128) K[(size_t)row * H + (n - 64)]  = f2bf(val);
            else              V[(size_t)row * H + (n - 128)] = f2bf(val);
        }
    }
}

// ---------------------------------------------------------------------------
// Kernel 3: VT[b][h][t] = V[b][t][h].  256 blocks x 256 thr, 64x64 tiles.
// ---------------------------------------------------------------------------
__global__ __launch_bounds__(256) void vtrans(const unsigned short* __restrict__ V,
                                              unsigned short* __restrict__ VT) {
    __shared__ __align__(16) unsigned short tile[64][72];
    const int b = blockIdx.x >> 6, t0 = (blockIdx.x & 63) * 64;
    const int tid = threadIdx.x;
    {
        int row = tid >> 2, col = (tid & 3) * 16;
        s16x8 v0 = *(const s16x8*)(V + (size_t)(b * T + t0 + row) * H + col);
        s16x8 v1 = *(const s16x8*)(V + (size_t)(b * T + t0 + row) * H + col + 8);
        *(s16x8*)&tile[row][col]     = v0;
        *(s16x8*)&tile[row][col + 8] = v1;
    }
    __syncthreads();
    {
        int h = tid >> 2, tcol = (tid & 3) * 16;
        s16x8 o0, o1;
#pragma unroll
        for (int j = 0; j < 8; ++j) o0[j] = (short)tile[tcol + j][h];
#pragma unroll
        for (int j = 0; j < 8; ++j) o1[j] = (short)tile[tcol + 8 + j][h];
        unsigned short* dst = VT + (size_t)(b * H + h) * T + t0 + tcol;
        *(s16x8*)dst       = o0;
        *(s16x8*)(dst + 8) = o1;
    }
}

// ---------------------------------------------------------------------------
// Kernel 4: causal flash attention.
// 512 blocks x 512 thr (8 waves).  Block = batch b, pair p: group 0 (waves
// 0-3) handles q-tile p, group 1 (waves 4-7) handles q-tile 255-p; within a
// group, wave sp handles KV tiles {sp, sp+4, ...}.  Barrier-free inner loop:
// K/VT fragments direct from global; P via per-wave swizzled LDS.
// Partial (m,l,O) merged across the 4 splits at the end.
// ---------------------------------------------------------------------------
__global__ __launch_bounds__(512, 4) void attn(
    const unsigned short* __restrict__ Qg, const unsigned short* __restrict__ Kg,
    const unsigned short* __restrict__ VTg, float* __restrict__ out) {
    __shared__ __align__(16) unsigned short ps[8][16 * 64];
    __shared__ __align__(16) float Olds[8][16][68];
    __shared__ float mS[8][16], lS[8][16];

    const int t = threadIdx.x, lane = t & 63, w = t >> 6;
    const int grp = w >> 2, sp = w & 3;
    const int p = blockIdx.x & 127, b = blockIdx.x >> 7;
    const int qt = grp ? (255 - p) : p;
    const int q0 = qt * 16;
    const int i = lane & 15, g = lane >> 4;

    const unsigned short* Qrow = Qg + (size_t)(b * T + q0 + i) * H;
    s16x8 aq0 = *(const s16x8*)(Qrow + g * 8);
    s16x8 aq1 = *(const s16x8*)(Qrow + 32 + g * 8);

    f32x4 oacc[4];
#pragma unroll
    for (int nt = 0; nt < 4; ++nt) oacc[nt] = (f32x4){0.f, 0.f, 0.f, 0.f};
    float m_run[4], l_run[4];
#pragma unroll
    for (int r = 0; r < 4; ++r) { m_run[r] = -INFINITY; l_run[r] = 0.f; }

    const int nkv = ((q0 + 15) >> 6) + 1;
    unsigned short* myps = ps[w];
    const unsigned short* Kb  = Kg  + (size_t)b * T * H;
    const unsigned short* Vb  = VTg + (size_t)b * H * T;

    for (int tile = sp; tile < nkv; tile += 4) {
        const int kv = tile * 64;

        // ---- K fragments (B-layout direct from global)
        s16x8 kb[8];
#pragma unroll
        for (int kst = 0; kst < 2; ++kst)
#pragma unroll
            for (int nt = 0; nt < 4; ++nt)
                kb[kst * 4 + nt] = *(const s16x8*)(Kb + (size_t)(kv + nt * 16 + i) * H + kst * 32 + g * 8);

        // ---- S = Q K^T
        f32x4 s[4];
#pragma unroll
        for (int nt = 0; nt < 4; ++nt) s[nt] = (f32x4){0.f, 0.f, 0.f, 0.f};
#pragma unroll
        for (int nt = 0; nt < 4; ++nt)
            s[nt] = __builtin_amdgcn_mfma_f32_16x16x32_bf16(aq0, kb[nt], s[nt], 0, 0, 0);
#pragma unroll
        for (int nt = 0; nt < 4; ++nt)
            s[nt] = __builtin_amdgcn_mfma_f32_16x16x32_bf16(aq1, kb[4 + nt], s[nt], 0, 0, 0);

        // ---- VT fragments for PV (issue early; independent of softmax)
        s16x8 vb[8];
#pragma unroll
        for (int kst = 0; kst < 2; ++kst)
#pragma unroll
            for (int nt = 0; nt < 4; ++nt)
                vb[kst * 4 + nt] = *(const s16x8*)(Vb + (size_t)(nt * 16 + i) * T + kv + kst * 32 + g * 8);

        // ---- causal mask: lane holds q = q0+4g+r, key = kv + nt*16 + i
        const int rq0 = q0 + g * 4;
#pragma unroll
        for (int nt = 0; nt < 4; ++nt) {
            int key = kv + nt * 16 + i;
#pragma unroll
            for (int r = 0; r < 4; ++r)
                if (key > rq0 + r) s[nt][r] = -INFINITY;
        }

        // ---- online softmax (key dim: 4 nt regs + 16-lane groups)
#pragma unroll
        for (int r = 0; r < 4; ++r) {
            float mx = fmaxf(fmaxf(s[0][r], s[1][r]), fmaxf(s[2][r], s[3][r]));
            mx = fmaxf(mx, __shfl_xor(mx, 1));
            mx = fmaxf(mx, __shfl_xor(mx, 2));
            mx = fmaxf(mx, __shfl_xor(mx, 4));
            mx = fmaxf(mx, __shfl_xor(mx, 8));
            float mnew = fmaxf(m_run[r], mx);
            float scale = exp2f((m_run[r] - mnew) * LOG2E);
            float rs = 0.f;
#pragma unroll
            for (int nt = 0; nt < 4; ++nt) {
                float pv = exp2f((s[nt][r] - mnew) * LOG2E);
                s[nt][r] = pv;
                rs += pv;
            }
            rs += __shfl_xor(rs, 1);
            rs += __shfl_xor(rs, 2);
            rs += __shfl_xor(rs, 4);
            rs += __shfl_xor(rs, 8);
            l_run[r] = l_run[r] * scale + rs;
            m_run[r] = mnew;
#pragma unroll
            for (int nt = 0; nt < 4; ++nt) oacc[nt][r] *= scale;
        }

        // ---- P (D-layout) -> per-wave LDS (swizzled) -> A-layout
#pragma unroll
        for (int nt = 0; nt < 4; ++nt) {
            int colk = nt * 16 + i;
#pragma unroll
            for (int r = 0; r < 4; ++r) {
                int row = g * 4 + r;
                myps[row * 64 + (colk ^ ((row & 7) << 3))] = f2bf(s[nt][r]);
            }
        }

        // ---- O += P V
#pragma unroll
        for (int kst = 0; kst < 2; ++kst) {
            s16x8 pa = *(const s16x8*)&myps[i * 64 + ((kst * 32 + g * 8) ^ ((i & 7) << 3))];
#pragma unroll
            for (int nt = 0; nt < 4; ++nt)
                oacc[nt] = __builtin_amdgcn_mfma_f32_16x16x32_bf16(pa, vb[kst * 4 + nt], oacc[nt], 0, 0, 0);
        }
    }

    // ---- write partial (m, l, O) and merge the 4 KV splits
#pragma unroll
    for (int nt = 0; nt < 4; ++nt)
#pragma unroll
        for (int r = 0; r < 4; ++r)
            Olds[w][g * 4 + r][nt * 16 + i] = oacc[nt][r];
    if (i == 0) {
#pragma unroll
        for (int r = 0; r < 4; ++r) { mS[w][g * 4 + r] = m_run[r]; lS[w][g * 4 + r] = l_run[r]; }
    }
    __syncthreads();

    {
        const int grp2 = t >> 8, idx = t & 255;
        const int q = idx >> 4, hc = (idx & 15) * 4;
        const int w0 = grp2 * 4;
        float Mx = fmaxf(fmaxf(mS[w0][q], mS[w0 + 1][q]), fmaxf(mS[w0 + 2][q], mS[w0 + 3][q]));
        float L = 0.f;
        f32x4 o = (f32x4){0.f, 0.f, 0.f, 0.f};
#pragma unroll
        for (int s4 = 0; s4 < 4; ++s4) {
            float wg = exp2f((mS[w0 + s4][q] - Mx) * LOG2E);
            L += wg * lS[w0 + s4][q];
            f32x4 ov = *(const f32x4*)&Olds[w0 + s4][q][hc];
            o[0] += wg * ov[0]; o[1] += wg * ov[1]; o[2] += wg * ov[2]; o[3] += wg * ov[3];
        }
        const int qq = (grp2 ? (255 - p) : p) * 16 + q;
        float inv = 1.0f / L;
        f32x4 res = (f32x4){o[0] * inv, o[1] * inv, o[2] * inv, o[3] * inv};
        *(f32x4*)(out + (size_t)(b * T + qq) * H + hc) = res;
    }
}

// ---------------------------------------------------------------------------
extern "C" void kernel_launch(void* const* d_in, const int* in_sizes, int n_in,
                              void* d_out, int out_size, void* d_ws, size_t ws_size,
                              hipStream_t stream) {
    (void)in_sizes; (void)n_in; (void)out_size; (void)ws_size;
    const float* x  = (const float*)d_in[0];
    const float* Wq = (const float*)d_in[1];
    const float* Wk = (const float*)d_in[2];
    const float* Wv = (const float*)d_in[3];
    float* out = (float*)d_out;

    char* ws = (char*)d_ws;
    unsigned short* Q  = (unsigned short*)(ws);
    unsigned short* K  = (unsigned short*)(ws + (size_t)1 * M * H * 2);
    unsigned short* V  = (unsigned short*)(ws + (size_t)2 * M * H * 2);
    unsigned short* VT = (unsigned short*)(ws + (size_t)3 * M * H * 2);
    unsigned short* Wt = (unsigned short*)(ws + (size_t)4 * M * H * 2);
    // workspace: 4*2MB + 384KB = 8.4MB

    prep_w<<<192, 256, 0, stream>>>(Wq, Wk, Wv, Wt);
    qkv_proj<<<M / 16, 256, 0, stream>>>(x, Wt, Q, K, V);
    vtrans<<<B * (T / 64), 256, 0, stream>>>(V, VT);
    attn<<<B * 128, 512, 0, stream>>>(Q, K, VT, out);
}